// Round 14
// baseline (2353.513 us; speedup 1.0000x reference)
//
#include <hip/hip_runtime.h>
#include <stdint.h>
#include <math.h>

#define NVARS 1024
#define KDIM 32
#define BATCH 64
#define NIN 768
#define MAXIT 10

// LDS layout (bytes) for the solve kernel:
//   Vs    @ 0       float [1024][32]   131072
//   Cd    @ 131072  float [64][64]      16384
//   dVs   @ 147456  float [64][32]       8192
//   fmask @ 155648  uint  [32]            128
//   v0D   @ 155776  double[32]            256
//   prog  @ 156032  int   [2]              64
#define SMEM_BYTES 156096

// LDS for the fused V+G kernel: Vls [1024][32] f32 + v0D double[32]
#define VG_SMEM (131072 + 256)

// workspace layout: V then G, each [64][1024][32] f32 = 8 MB
#define WS_V_OFF 0
#define WS_G_OFF (64ull * 1024 * 32 * 4)
#define WS_NEEDED (2ull * 64 * 1024 * 32 * 4)

typedef float f32x2 __attribute__((ext_vector_type(2)));

#define PKSETUP(A0v, A1v, Dv)                                                  \
    const float4 A0_ = (A0v), A1_ = (A1v), d_ = (Dv);                          \
    f32x2 c01, c23, c45, c67, dx_, dy_, dz_, dw_;                              \
    c01.x = A0_.x; c01.y = A0_.y; c23.x = A0_.z; c23.y = A0_.w;                \
    c45.x = A1_.x; c45.y = A1_.y; c67.x = A1_.z; c67.y = A1_.w;                \
    dx_.x = d_.x;  dx_.y = d_.x;  dy_.x = d_.y;  dy_.y = d_.y;                 \
    dz_.x = d_.z;  dz_.y = d_.z;  dw_.x = d_.w;  dw_.y = d_.w;

#define PKG0                                                                   \
    Q0_0 = __builtin_elementwise_fma(c01, dx_, Q0_0);                          \
    Q1_0 = __builtin_elementwise_fma(c01, dy_, Q1_0);                          \
    Q2_0 = __builtin_elementwise_fma(c01, dz_, Q2_0);                          \
    Q3_0 = __builtin_elementwise_fma(c01, dw_, Q3_0);
#define PKG1                                                                   \
    Q0_1 = __builtin_elementwise_fma(c23, dx_, Q0_1);                          \
    Q1_1 = __builtin_elementwise_fma(c23, dy_, Q1_1);                          \
    Q2_1 = __builtin_elementwise_fma(c23, dz_, Q2_1);                          \
    Q3_1 = __builtin_elementwise_fma(c23, dw_, Q3_1);
#define PKG2                                                                   \
    Q0_2 = __builtin_elementwise_fma(c45, dx_, Q0_2);                          \
    Q1_2 = __builtin_elementwise_fma(c45, dy_, Q1_2);                          \
    Q2_2 = __builtin_elementwise_fma(c45, dz_, Q2_2);                          \
    Q3_2 = __builtin_elementwise_fma(c45, dw_, Q3_2);
#define PKG3                                                                   \
    Q0_3 = __builtin_elementwise_fma(c67, dx_, Q0_3);                          \
    Q1_3 = __builtin_elementwise_fma(c67, dy_, Q1_3);                          \
    Q2_3 = __builtin_elementwise_fma(c67, dz_, Q2_3);                          \
    Q3_3 = __builtin_elementwise_fma(c67, dw_, Q3_3);

#define PKROWR(A0v, A1v, Dv, Ra, Rb, Rc, Rd)                                   \
  { PKSETUP(A0v, A1v, Dv) PKG##Ra PKG##Rb PKG##Rc PKG##Rd }
#define PKROW(A0v, A1v, Dv) PKROWR(A0v, A1v, Dv, 0, 1, 2, 3)

// ---- threefry2x32 block, exactly matching JAX (20 rounds, inject every 4) ----
__device__ __forceinline__ void tf2x32(uint32_t key0, uint32_t key1,
                                       uint32_t& x0, uint32_t& x1) {
  uint32_t ks2 = key0 ^ key1 ^ 0x1BD11BDAu;
  x0 += key0; x1 += key1;
#define TFR(r) { x0 += x1; x1 = (x1 << r) | (x1 >> (32 - r)); x1 ^= x0; }
  TFR(13) TFR(15) TFR(26) TFR(6)
  x0 += key1; x1 += ks2 + 1u;
  TFR(17) TFR(29) TFR(16) TFR(24)
  x0 += ks2;  x1 += key0 + 2u;
  TFR(13) TFR(15) TFR(26) TFR(6)
  x0 += key0; x1 += key1 + 3u;
  TFR(17) TFR(29) TFR(16) TFR(24)
  x0 += key1; x1 += ks2 + 4u;
  TFR(13) TFR(15) TFR(26) TFR(6)
  x0 += ks2;  x1 += key0 + 5u;
#undef TFR
}

__device__ __forceinline__ uint32_t pbits(uint32_t k0, uint32_t k1, uint32_t flat) {
  uint32_t x0 = 0u, x1 = flat;
  tf2x32(k0, k1, x0, x1);
  return x0 ^ x1;
}

// ---- XLA f32 erf_inv (Giles polynomial) ----
__device__ __forceinline__ float erfinv_xla(float x) {
  float w = -log1pf(-x * x);
  float p;
  if (w < 5.0f) {
    w -= 2.5f;
    p = 2.81022636e-08f;
    p = fmaf(p, w, 3.43273939e-07f);
    p = fmaf(p, w, -3.5233877e-06f);
    p = fmaf(p, w, -4.39150654e-06f);
    p = fmaf(p, w, 0.00021858087f);
    p = fmaf(p, w, -0.00125372503f);
    p = fmaf(p, w, -0.00417768164f);
    p = fmaf(p, w, 0.246640727f);
    p = fmaf(p, w, 1.50140941f);
  } else {
    w = sqrtf(w) - 3.0f;
    p = -0.000200214257f;
    p = fmaf(p, w, 0.000100950558f);
    p = fmaf(p, w, 0.00134934322f);
    p = fmaf(p, w, -0.00367342844f);
    p = fmaf(p, w, 0.00573950773f);
    p = fmaf(p, w, -0.0076224613f);
    p = fmaf(p, w, 0.00943887047f);
    p = fmaf(p, w, 1.00167406f);
    p = fmaf(p, w, 2.83297682f);
  }
  return p * x;
}

__device__ __forceinline__ float bits_to_normal(uint32_t bits) {
  uint32_t fb = (bits >> 9) | 0x3F800000u;
  float f = __uint_as_float(fb) - 1.0f;
  const float lo = -0.99999994f;
  float u = fmaf(f, 2.0f, lo);
  u = fmaxf(lo, u);
  return 1.41421356237f * erfinv_xla(u);
}

__device__ __forceinline__ double red32d(double v) {
  v += __shfl_xor(v, 16);
  v += __shfl_xor(v, 8);
  v += __shfl_xor(v, 4);
  v += __shfl_xor(v, 2);
  v += __shfl_xor(v, 1);
  return v;
}

__device__ __forceinline__ int pop64(uint64_t& b) {
  if (b == 0ull) return -1;
  int i = (int)__builtin_ctzll(b);
  b &= b - 1ull;
  return i;
}

template <int CTRL>
__device__ __forceinline__ float dppadd(float s) {
  int v = __builtin_amdgcn_update_dpp(0, __float_as_int(s), CTRL, 0xF, 0xF, true);
  return s + __int_as_float(v);
}

// shared V-row builder (f64 in-thread, bitwise identical to monolithic path)
__device__ __forceinline__ void build_vrow(int b, int row, const float* zin,
                                           const int* is_in, const double* v0D,
                                           double* vrow) {
  const double PI_D = 3.14159265358979323846;
  uint32_t b0 = 0u, b1 = 1u; tf2x32(0u, 42u, b0, b1);
  if (row == 0) {
#pragma unroll
    for (int t = 0; t < 16; ++t) {
      double2 w = *(const double2*)(v0D + 2 * t);
      vrow[2 * t] = w.x; vrow[2 * t + 1] = w.y;
    }
  } else {
    uint32_t base = ((uint32_t)(b * NVARS + row)) * KDIM;
#pragma unroll
    for (int q = 0; q < 32; ++q)
      vrow[q] = (double)bits_to_normal(pbits(b0, b1, base + (uint32_t)q));
    double dot = 0.0;
#pragma unroll
    for (int t = 0; t < 16; ++t) {
      double2 w = *(const double2*)(v0D + 2 * t);
      dot += vrow[2 * t] * w.x + vrow[2 * t + 1] * w.y;
    }
#pragma unroll
    for (int t = 0; t < 16; ++t) {
      double2 w = *(const double2*)(v0D + 2 * t);
      vrow[2 * t]     -= dot * w.x;
      vrow[2 * t + 1] -= dot * w.y;
    }
    double n2 = 0.0;
#pragma unroll
    for (int q = 0; q < 32; ++q) n2 += vrow[q] * vrow[q];
    double rinv = 1.0 / sqrt(n2);
#pragma unroll
    for (int q = 0; q < 32; ++q) vrow[q] *= rinv;
    if (row <= NIN && is_in[b * NIN + row - 1] > 0) {
      double zf = (double)zin[b * NIN + row - 1];
      double cc = cos(PI_D * zf), sn = sin(PI_D * zf);
#pragma unroll
      for (int t = 0; t < 16; ++t) {
        double2 w = *(const double2*)(v0D + 2 * t);
        vrow[2 * t]     = -cc * w.x + sn * vrow[2 * t];
        vrow[2 * t + 1] = -cc * w.y + sn * vrow[2 * t + 1];
      }
    }
  }
}

// ====== fused kernel: V (per-batch, in-LDS) + G quarter -> ws (256 x 1024) =
__global__ __launch_bounds__(1024) void mixnet_vg(
    const float* __restrict__ C32, const float* __restrict__ zin,
    const int* __restrict__ is_in, float* __restrict__ Vw,
    float* __restrict__ Gw) {
  extern __shared__ char smemraw[];
  float*  Vls = (float*)smemraw;               // [1024][32]
  double* v0D = (double*)(smemraw + 131072);   // [32]

  const int tid = threadIdx.x;
  const int b = blockIdx.x >> 2, q = blockIdx.x & 3;

  uint32_t a0 = 0u, a1 = 0u; tf2x32(0u, 42u, a0, a1);
  if (tid < 32) {
    float raw = bits_to_normal(pbits(a0, a1, (uint32_t)(b * KDIM + tid)));
    double n2 = red32d((double)raw * (double)raw);
    v0D[tid] = (double)raw / sqrt(n2);
  }
  __syncthreads();

  {
    double vrow[32];
    build_vrow(b, tid, zin, is_in, v0D, vrow);
    const bool ownq = ((tid >> 8) == q);   // this block owns V quarter q
#pragma unroll
    for (int qq = 0; qq < 8; ++qq) {
      float4 w;
      w.x = (float)vrow[4 * qq];     w.y = (float)vrow[4 * qq + 1];
      w.z = (float)vrow[4 * qq + 2]; w.w = (float)vrow[4 * qq + 3];
      *(float4*)(Vls + tid * 32 + 4 * qq) = w;
      if (ownq)
        *(float4*)(Vw + (size_t)(b * NVARS + tid) * 32 + 4 * qq) = w;
    }
  }
  __syncthreads();

  const int jg2 = tid >> 3, kg = tid & 7;
  const int r0 = q * 256 + 2 * jg2;
  const float* Cb0 = C32 + (size_t)r0 * NVARS;
  const float* Cb1 = Cb0 + NVARS;

  float G0 = 0.f, G1 = 0.f, G2 = 0.f, G3 = 0.f;
  float G4 = 0.f, G5 = 0.f, G6 = 0.f, G7 = 0.f;
  for (int i = 0; i < NVARS; i += 4) {
    float4 c0 = *(const float4*)(Cb0 + i);
    float4 c1 = *(const float4*)(Cb1 + i);
#pragma unroll
    for (int u = 0; u < 4; ++u) {
      float4 vv = *(const float4*)(Vls + (i + u) * 32 + 4 * kg);
      float cu0 = (u == 0) ? c0.x : (u == 1) ? c0.y : (u == 2) ? c0.z : c0.w;
      float cu1 = (u == 0) ? c1.x : (u == 1) ? c1.y : (u == 2) ? c1.z : c1.w;
      G0 = fmaf(cu0, vv.x, G0); G1 = fmaf(cu0, vv.y, G1);
      G2 = fmaf(cu0, vv.z, G2); G3 = fmaf(cu0, vv.w, G3);
      G4 = fmaf(cu1, vv.x, G4); G5 = fmaf(cu1, vv.y, G5);
      G6 = fmaf(cu1, vv.z, G6); G7 = fmaf(cu1, vv.w, G7);
    }
  }
  float4 w0; w0.x = G0; w0.y = G1; w0.z = G2; w0.w = G3;
  float4 w1; w1.x = G4; w1.y = G5; w1.z = G6; w1.w = G7;
  *(float4*)(Gw + (size_t)(b * NVARS + r0) * 32 + 4 * kg)     = w0;
  *(float4*)(Gw + (size_t)(b * NVARS + r0 + 1) * 32 + 4 * kg) = w1;
}

// ---- producer row (R11 form: raw rsq, rotated PKROW) ----
#define PROW(iiL, mL, pL, cL, Ra, Rb, Rc, Rd)                                  \
  {                                                                            \
    const bool on = ((iiL) < 32) ? ((myLo >> (iiL)) & 1u)                      \
                                 : ((myHi >> ((iiL) - 32)) & 1u);              \
    if (on) {                                                                  \
      const int row = base + (iiL);                                            \
      float4 c0 = *(const float4*)(Cd + (iiL) * 64 + 8 * jgR);                 \
      float4 c1 = *(const float4*)(Cd + (iiL) * 64 + 8 * jgR + 4);             \
      float4 vold = *(const float4*)(Vs + row * 32 + 4 * kg);                  \
      const float g0 = (Q0_##pL).cL, g1 = (Q1_##pL).cL;                        \
      const float g2 = (Q2_##pL).cL, g3 = (Q3_##pL).cL;                        \
      float s = g0 * g0;                                                       \
      s = fmaf(g1, g1, s); s = fmaf(g2, g2, s); s = fmaf(g3, g3, s);           \
      s = dppadd<0xB1>(s);                                                     \
      s = dppadd<0x4E>(s);                                                     \
      s = dppadd<0x141>(s);                                                    \
      const float sc = fmaxf(s, 1e-24f);                                       \
      const float inv = -__builtin_amdgcn_rsqf(sc);                            \
      float4 vnew, d;                                                          \
      vnew.x = g0 * inv; d.x = vnew.x - vold.x;                                \
      vnew.y = g1 * inv; d.y = vnew.y - vold.y;                                \
      vnew.z = g2 * inv; d.z = vnew.z - vold.z;                                \
      vnew.w = g3 * inv; d.w = vnew.w - vold.w;                                \
      if (jgR == (mL)) *(float4*)(dVs + n * 32 + 4 * kg) = d;                  \
      asm volatile("" ::: "memory");                                           \
      if (lane == 0) progV[spar] = n + 1;                                      \
      float4 dd = *(const float4*)(dVs + n * 32 + 4 * kg);                     \
      if (jgR == (mL)) *(float4*)(Vs + row * 32 + 4 * kg) = vnew;              \
      PKROWR(c0, c1, dd, Ra, Rb, Rc, Rd);                                      \
      ++n;                                                                     \
    }                                                                          \
  }

#define PGRP(mL)                                                               \
  PROW(8 * (mL) + 0, mL, 0, x, 0, 1, 2, 3)                                     \
  PROW(8 * (mL) + 1, mL, 0, y, 1, 2, 3, 0)                                     \
  PROW(8 * (mL) + 2, mL, 1, x, 1, 2, 3, 0)                                     \
  PROW(8 * (mL) + 3, mL, 1, y, 2, 3, 0, 1)                                     \
  PROW(8 * (mL) + 4, mL, 2, x, 2, 3, 0, 1)                                     \
  PROW(8 * (mL) + 5, mL, 2, y, 3, 0, 1, 2)                                     \
  PROW(8 * (mL) + 6, mL, 3, x, 3, 0, 1, 2)                                     \
  PROW(8 * (mL) + 7, mL, 3, y, 0, 1, 2, 3)

// ================= solve kernel (64 blocks x 1024 thr) =====================
// R14 change (single variable): Cd staging via register prefetch (T14).
// At span start we WRITE the register held from one span ago (LDS-only,
// fast), then immediately ISSUE the next span's global C load — its ~L2
// latency hides under the whole span's compute instead of stalling the
// span-start barrier. Same loads, same data => bit-identical.
__global__ __launch_bounds__(1024, 4) void mixnet_solve(
    const float* __restrict__ C32, const float* __restrict__ zin,
    const int* __restrict__ is_in, const float* __restrict__ Vw,
    const float* __restrict__ Gw, float* __restrict__ out) {
  extern __shared__ char smemraw[];
  float*    Vs    = (float*)smemraw;
  float*    Cd    = (float*)(smemraw + 131072);
  float*    dVs   = (float*)(smemraw + 147456);
  uint32_t* fmask = (uint32_t*)(smemraw + 155648);
  double*   v0D   = (double*)(smemraw + 155776);
  volatile int* progV = (volatile int*)(smemraw + 156032);

  const int tid  = threadIdx.x;
  const int b    = blockIdx.x;
  const int jg   = tid >> 3;
  const int kg   = tid & 7;
  const int lane = tid & 63;
  const int wave = tid >> 6;
  const int jgR  = jg & 7;

  uint32_t myLo, myHi;
  {
    int row = tid;
    bool fr;
    if (row == 0) fr = false;
    else if (row <= NIN) fr = (is_in[b * NIN + row - 1] == 0);
    else fr = true;
    unsigned long long m = __ballot(fr);
    myLo = (uint32_t)m; myHi = (uint32_t)(m >> 32);
    if (lane == 0) { fmask[2 * wave] = myLo; fmask[2 * wave + 1] = myHi; }
  }
  if (tid == 0) { progV[0] = 0; progV[1] = 0; }

  uint32_t a0 = 0u, a1 = 0u; tf2x32(0u, 42u, a0, a1);
  if (tid < 32) {
    float raw = bits_to_normal(pbits(a0, a1, (uint32_t)(b * KDIM + tid)));
    double n2 = red32d((double)raw * (double)raw);
    v0D[tid] = (double)raw / sqrt(n2);
  }

  {
    const float* vp = Vw + (size_t)(b * NVARS + tid) * 32;
#pragma unroll
    for (int qq = 0; qq < 8; ++qq)
      *(float4*)(Vs + tid * 32 + 4 * qq) = *(const float4*)(vp + 4 * qq);
  }

  f32x2 Q0_0, Q1_0, Q2_0, Q3_0, Q0_1, Q1_1, Q2_1, Q3_1;
  f32x2 Q0_2, Q1_2, Q2_2, Q3_2, Q0_3, Q1_3, Q2_3, Q3_3;
  {
    const float* gp = Gw + (size_t)(b * NVARS + 8 * jg) * 32 + 4 * kg;
    float4 g0 = *(const float4*)(gp + 0 * 32);
    float4 g1 = *(const float4*)(gp + 1 * 32);
    float4 g2 = *(const float4*)(gp + 2 * 32);
    float4 g3 = *(const float4*)(gp + 3 * 32);
    float4 g4 = *(const float4*)(gp + 4 * 32);
    float4 g5 = *(const float4*)(gp + 5 * 32);
    float4 g6 = *(const float4*)(gp + 6 * 32);
    float4 g7 = *(const float4*)(gp + 7 * 32);
    Q0_0.x = g0.x; Q0_0.y = g1.x; Q1_0.x = g0.y; Q1_0.y = g1.y;
    Q2_0.x = g0.z; Q2_0.y = g1.z; Q3_0.x = g0.w; Q3_0.y = g1.w;
    Q0_1.x = g2.x; Q0_1.y = g3.x; Q1_1.x = g2.y; Q1_1.y = g3.y;
    Q2_1.x = g2.z; Q2_1.y = g3.z; Q3_1.x = g2.w; Q3_1.y = g3.w;
    Q0_2.x = g4.x; Q0_2.y = g5.x; Q1_2.x = g4.y; Q1_2.y = g5.y;
    Q2_2.x = g4.z; Q2_2.y = g5.z; Q3_2.x = g4.w; Q3_2.y = g5.w;
    Q0_3.x = g6.x; Q0_3.y = g7.x; Q1_3.x = g6.y; Q1_3.y = g7.y;
    Q2_3.x = g6.z; Q2_3.y = g7.z; Q3_3.x = g6.w; Q3_3.y = g7.w;
  }

  // staging prefetch prologue: load span 0's Cd block into registers
  const int srow = tid >> 4, sc4 = (tid & 15) << 2;
  float4 cc_next = *(const float4*)(C32 + (size_t)srow * NVARS + sc4); // g=0
  __syncthreads();

  int spar = 0;
  for (int it = 0; it < MAXIT; ++it) {
    for (int g = 0; g < 16; ++g) {
      // write previously-loaded Cd block (LDS-only; no global latency here)
      *(float4*)(Cd + srow * 64 + sc4) = cc_next;
      // issue NEXT span's load now — latency hides under this span's compute
      {
        const int gn = (g == 15) ? 0 : g + 1;
        cc_next = *(const float4*)(C32 + (size_t)(64 * gn + srow) * NVARS
                                   + 64 * gn + sc4);
      }
      const uint32_t fl = fmask[2 * g], fh = fmask[2 * g + 1];
      if (wave == g && lane == 0) progV[spar ^ 1] = 0;
      __syncthreads();

      if (wave == g) {
        __builtin_amdgcn_s_setprio(3);
        int n = 0;
        const int base = 64 * g;
        PGRP(0) PGRP(1) PGRP(2) PGRP(3)
        PGRP(4) PGRP(5) PGRP(6) PGRP(7)
        __builtin_amdgcn_s_setprio(0);
      } else {
        uint64_t pb = ((uint64_t)fh << 32) | (uint64_t)fl;
        const int cnt = (int)__builtin_popcountll(pb);
        float4 cp0[4], cp1[4];
#pragma unroll
        for (int s2 = 0; s2 < 4; ++s2) {
          int r = pop64(pb);
          if (r >= 0) {
            const float* p = C32 + (size_t)(64 * g + r) * NVARS + 8 * jg;
            cp0[s2] = *(const float4*)p; cp1[s2] = *(const float4*)(p + 4);
          }
        }
        int n2 = 0;
        while (n2 < cnt) {
          const int hi = (n2 + 4 < cnt) ? n2 + 4 : cnt;
          while (progV[spar] < hi) __builtin_amdgcn_s_sleep(8);
          if (hi == n2 + 4) {
            float4 dq0 = *(const float4*)(dVs + (n2 + 0) * 32 + 4 * kg);
            float4 dq1 = *(const float4*)(dVs + (n2 + 1) * 32 + 4 * kg);
            float4 dq2 = *(const float4*)(dVs + (n2 + 2) * 32 + 4 * kg);
            float4 dq3 = *(const float4*)(dVs + (n2 + 3) * 32 + 4 * kg);
            PKROW(cp0[0], cp1[0], dq0);
            PKROW(cp0[1], cp1[1], dq1);
            PKROW(cp0[2], cp1[2], dq2);
            PKROW(cp0[3], cp1[3], dq3);
          } else {
#pragma unroll
            for (int s2 = 0; s2 < 4; ++s2) {
              if (n2 + s2 < hi) {
                float4 dv = *(const float4*)(dVs + (n2 + s2) * 32 + 4 * kg);
                PKROW(cp0[s2], cp1[s2], dv);
              }
            }
          }
#pragma unroll
          for (int s2 = 0; s2 < 4; ++s2) {
            int r = pop64(pb);
            if (r >= 0) {
              const float* p = C32 + (size_t)(64 * g + r) * NVARS + 8 * jg;
              cp0[s2] = *(const float4*)p; cp1[s2] = *(const float4*)(p + 4);
            }
          }
          n2 = hi;
        }
      }
      spar ^= 1;
      __syncthreads();
    }
  }

  const double PI_D = 3.14159265358979323846;
  if (tid >= 1 && tid <= NIN) {
    bool fr = (fmask[tid >> 5] >> (tid & 31)) & 1u;
    float zo;
    if (fr) {
      double dot = 0.0;
#pragma unroll
      for (int t = 0; t < 16; ++t) {
        double2 w = *(const double2*)(v0D + 2 * t);
        dot += (double)Vs[tid * 32 + 2 * t] * w.x
             + (double)Vs[tid * 32 + 2 * t + 1] * w.y;
      }
      double ca = fmin(fmax(-dot, -1.0 + 1e-7), 1.0 - 1e-7);
      zo = (float)(acos(ca) / PI_D);
    } else {
      zo = zin[b * NIN + tid - 1];
    }
    out[b * NIN + tid - 1] = zo;
  }
}

// ============== monolithic fallback (R11 verbatim) =========================
__global__ __launch_bounds__(1024, 4) void mixnet_kernel(
    const float* __restrict__ C32, const float* __restrict__ zin,
    const int* __restrict__ is_in, float* __restrict__ out) {
  extern __shared__ char smemraw[];
  float*    Vs    = (float*)smemraw;
  float*    Cd    = (float*)(smemraw + 131072);
  float*    dVs   = (float*)(smemraw + 147456);
  uint32_t* fmask = (uint32_t*)(smemraw + 155648);
  double*   v0D   = (double*)(smemraw + 155776);
  volatile int* progV = (volatile int*)(smemraw + 156032);

  const int tid  = threadIdx.x;
  const int b    = blockIdx.x;
  const int jg   = tid >> 3;
  const int kg   = tid & 7;
  const int lane = tid & 63;
  const int wave = tid >> 6;
  const int jgR  = jg & 7;

  uint32_t myLo, myHi;
  {
    int row = tid;
    bool fr;
    if (row == 0) fr = false;
    else if (row <= NIN) fr = (is_in[b * NIN + row - 1] == 0);
    else fr = true;
    unsigned long long m = __ballot(fr);
    myLo = (uint32_t)m; myHi = (uint32_t)(m >> 32);
    if (lane == 0) { fmask[2 * wave] = myLo; fmask[2 * wave + 1] = myHi; }
  }
  if (tid == 0) { progV[0] = 0; progV[1] = 0; }

  uint32_t a0 = 0u, a1 = 0u; tf2x32(0u, 42u, a0, a1);
  if (tid < 32) {
    float raw = bits_to_normal(pbits(a0, a1, (uint32_t)(b * KDIM + tid)));
    double n2 = red32d((double)raw * (double)raw);
    v0D[tid] = (double)raw / sqrt(n2);
  }
  __syncthreads();

  {
    double vrow[32];
    build_vrow(b, tid, zin, is_in, v0D, vrow);
#pragma unroll
    for (int q = 0; q < 8; ++q) {
      float4 w;
      w.x = (float)vrow[4 * q];     w.y = (float)vrow[4 * q + 1];
      w.z = (float)vrow[4 * q + 2]; w.w = (float)vrow[4 * q + 3];
      *(float4*)(Vs + tid * 32 + 4 * q) = w;
    }
  }
  __syncthreads();

  f32x2 Q0_0, Q1_0, Q2_0, Q3_0, Q0_1, Q1_1, Q2_1, Q3_1;
  f32x2 Q0_2, Q1_2, Q2_2, Q3_2, Q0_3, Q1_3, Q2_3, Q3_3;
  {
    float Gj[32];
#pragma unroll
    for (int q = 0; q < 32; ++q) Gj[q] = 0.f;
    const float* Cb = C32 + (size_t)(8 * jg) * NVARS;
    for (int i = 0; i < NVARS; i += 4) {
      float4 cw[8];
#pragma unroll
      for (int l = 0; l < 8; ++l)
        cw[l] = *(const float4*)(Cb + (size_t)l * NVARS + i);
#pragma unroll
      for (int u = 0; u < 4; ++u) {
        float4 vv = *(const float4*)(Vs + (i + u) * 32 + 4 * kg);
#pragma unroll
        for (int l = 0; l < 8; ++l) {
          float cu = (u == 0) ? cw[l].x : (u == 1) ? cw[l].y
                   : (u == 2) ? cw[l].z : cw[l].w;
          Gj[l * 4 + 0] = fmaf(cu, vv.x, Gj[l * 4 + 0]);
          Gj[l * 4 + 1] = fmaf(cu, vv.y, Gj[l * 4 + 1]);
          Gj[l * 4 + 2] = fmaf(cu, vv.z, Gj[l * 4 + 2]);
          Gj[l * 4 + 3] = fmaf(cu, vv.w, Gj[l * 4 + 3]);
        }
      }
    }
    Q0_0.x = Gj[0];  Q0_0.y = Gj[4];  Q1_0.x = Gj[1];  Q1_0.y = Gj[5];
    Q2_0.x = Gj[2];  Q2_0.y = Gj[6];  Q3_0.x = Gj[3];  Q3_0.y = Gj[7];
    Q0_1.x = Gj[8];  Q0_1.y = Gj[12]; Q1_1.x = Gj[9];  Q1_1.y = Gj[13];
    Q2_1.x = Gj[10]; Q2_1.y = Gj[14]; Q3_1.x = Gj[11]; Q3_1.y = Gj[15];
    Q0_2.x = Gj[16]; Q0_2.y = Gj[20]; Q1_2.x = Gj[17]; Q1_2.y = Gj[21];
    Q2_2.x = Gj[18]; Q2_2.y = Gj[22]; Q3_2.x = Gj[19]; Q3_2.y = Gj[23];
    Q0_3.x = Gj[24]; Q0_3.y = Gj[28]; Q1_3.x = Gj[25]; Q1_3.y = Gj[29];
    Q2_3.x = Gj[26]; Q2_3.y = Gj[30]; Q3_3.x = Gj[27]; Q3_3.y = Gj[31];
  }
  __syncthreads();

  int spar = 0;
  for (int it = 0; it < MAXIT; ++it) {
    for (int g = 0; g < 16; ++g) {
      {
        int r = tid >> 4, c4 = (tid & 15) << 2;
        float4 cc = *(const float4*)(C32 + (size_t)(64 * g + r) * NVARS
                                     + 64 * g + c4);
        *(float4*)(Cd + r * 64 + c4) = cc;
      }
      const uint32_t fl = fmask[2 * g], fh = fmask[2 * g + 1];
      if (wave == g && lane == 0) progV[spar ^ 1] = 0;
      __syncthreads();

      if (wave == g) {
        __builtin_amdgcn_s_setprio(3);
        int n = 0;
        const int base = 64 * g;
        PGRP(0) PGRP(1) PGRP(2) PGRP(3)
        PGRP(4) PGRP(5) PGRP(6) PGRP(7)
        __builtin_amdgcn_s_setprio(0);
      } else {
        uint64_t pb = ((uint64_t)fh << 32) | (uint64_t)fl;
        const int cnt = (int)__builtin_popcountll(pb);
        float4 cp0[4], cp1[4];
#pragma unroll
        for (int s2 = 0; s2 < 4; ++s2) {
          int r = pop64(pb);
          if (r >= 0) {
            const float* p = C32 + (size_t)(64 * g + r) * NVARS + 8 * jg;
            cp0[s2] = *(const float4*)p; cp1[s2] = *(const float4*)(p + 4);
          }
        }
        int n2 = 0;
        while (n2 < cnt) {
          const int hi = (n2 + 4 < cnt) ? n2 + 4 : cnt;
          while (progV[spar] < hi) __builtin_amdgcn_s_sleep(8);
          if (hi == n2 + 4) {
            float4 dq0 = *(const float4*)(dVs + (n2 + 0) * 32 + 4 * kg);
            float4 dq1 = *(const float4*)(dVs + (n2 + 1) * 32 + 4 * kg);
            float4 dq2 = *(const float4*)(dVs + (n2 + 2) * 32 + 4 * kg);
            float4 dq3 = *(const float4*)(dVs + (n2 + 3) * 32 + 4 * kg);
            PKROW(cp0[0], cp1[0], dq0);
            PKROW(cp0[1], cp1[1], dq1);
            PKROW(cp0[2], cp1[2], dq2);
            PKROW(cp0[3], cp1[3], dq3);
          } else {
#pragma unroll
            for (int s2 = 0; s2 < 4; ++s2) {
              if (n2 + s2 < hi) {
                float4 dv = *(const float4*)(dVs + (n2 + s2) * 32 + 4 * kg);
                PKROW(cp0[s2], cp1[s2], dv);
              }
            }
          }
#pragma unroll
          for (int s2 = 0; s2 < 4; ++s2) {
            int r = pop64(pb);
            if (r >= 0) {
              const float* p = C32 + (size_t)(64 * g + r) * NVARS + 8 * jg;
              cp0[s2] = *(const float4*)p; cp1[s2] = *(const float4*)(p + 4);
            }
          }
          n2 = hi;
        }
      }
      spar ^= 1;
      __syncthreads();
    }
  }

  const double PI_D = 3.14159265358979323846;
  if (tid >= 1 && tid <= NIN) {
    bool fr = (fmask[tid >> 5] >> (tid & 31)) & 1u;
    float zo;
    if (fr) {
      double dot = 0.0;
#pragma unroll
      for (int t = 0; t < 16; ++t) {
        double2 w = *(const double2*)(v0D + 2 * t);
        dot += (double)Vs[tid * 32 + 2 * t] * w.x
             + (double)Vs[tid * 32 + 2 * t + 1] * w.y;
      }
      double ca = fmin(fmax(-dot, -1.0 + 1e-7), 1.0 - 1e-7);
      zo = (float)(acos(ca) / PI_D);
    } else {
      zo = zin[b * NIN + tid - 1];
    }
    out[b * NIN + tid - 1] = zo;
  }
}

extern "C" void kernel_launch(void* const* d_in, const int* in_sizes, int n_in,
                              void* d_out, int out_size, void* d_ws, size_t ws_size,
                              hipStream_t stream) {
  const float* C        = (const float*)d_in[0];
  const float* z        = (const float*)d_in[1];
  const int*   is_input = (const int*)d_in[2];
  float*       out      = (float*)d_out;

  (void)hipFuncSetAttribute((const void*)mixnet_vg,
                            hipFuncAttributeMaxDynamicSharedMemorySize,
                            VG_SMEM);
  (void)hipFuncSetAttribute((const void*)mixnet_solve,
                            hipFuncAttributeMaxDynamicSharedMemorySize,
                            SMEM_BYTES);
  (void)hipFuncSetAttribute((const void*)mixnet_kernel,
                            hipFuncAttributeMaxDynamicSharedMemorySize,
                            SMEM_BYTES);

  if (d_ws != nullptr && ws_size >= WS_NEEDED) {
    float* Vw = (float*)((char*)d_ws + WS_V_OFF);
    float* Gw = (float*)((char*)d_ws + WS_G_OFF);
    mixnet_vg<<<256, 1024, VG_SMEM, stream>>>(C, z, is_input, Vw, Gw);
    mixnet_solve<<<BATCH, 1024, SMEM_BYTES, stream>>>(C, z, is_input, Vw, Gw, out);
  } else {
    mixnet_kernel<<<BATCH, 1024, SMEM_BYTES, stream>>>(C, z, is_input, out);
  }
}

// Round 15
// 2114.100 us; speedup vs baseline: 1.1132x; 1.1132x over previous
//
#include <hip/hip_runtime.h>
#include <stdint.h>
#include <math.h>

#define NVARS 1024
#define KDIM 32
#define BATCH 64
#define NIN 768
#define MAXIT 10

// LDS layout (bytes) for the solve kernel:
//   Vs    @ 0       float [1024][32]   131072
//   Cd    @ 131072  float [64][64]      16384
//   dVs   @ 147456  float [64][32]       8192
//   fmask @ 155648  uint  [32]            128
//   v0D   @ 155776  double[32]            256
//   prog  @ 156032  int   [2]              64
#define SMEM_BYTES 156096

// LDS for the fused V+G kernel: Vls [1024][32] f32 + v0D double[32]
#define VG_SMEM (131072 + 256)

// workspace layout: V then G, each [64][1024][32] f32 = 8 MB
#define WS_V_OFF 0
#define WS_G_OFF (64ull * 1024 * 32 * 4)
#define WS_NEEDED (2ull * 64 * 1024 * 32 * 4)

typedef float f32x2 __attribute__((ext_vector_type(2)));

#define PKSETUP(A0v, A1v, Dv)                                                  \
    const float4 A0_ = (A0v), A1_ = (A1v), d_ = (Dv);                          \
    f32x2 c01, c23, c45, c67, dx_, dy_, dz_, dw_;                              \
    c01.x = A0_.x; c01.y = A0_.y; c23.x = A0_.z; c23.y = A0_.w;                \
    c45.x = A1_.x; c45.y = A1_.y; c67.x = A1_.z; c67.y = A1_.w;                \
    dx_.x = d_.x;  dx_.y = d_.x;  dy_.x = d_.y;  dy_.y = d_.y;                 \
    dz_.x = d_.z;  dz_.y = d_.z;  dw_.x = d_.w;  dw_.y = d_.w;

#define PKG0                                                                   \
    Q0_0 = __builtin_elementwise_fma(c01, dx_, Q0_0);                          \
    Q1_0 = __builtin_elementwise_fma(c01, dy_, Q1_0);                          \
    Q2_0 = __builtin_elementwise_fma(c01, dz_, Q2_0);                          \
    Q3_0 = __builtin_elementwise_fma(c01, dw_, Q3_0);
#define PKG1                                                                   \
    Q0_1 = __builtin_elementwise_fma(c23, dx_, Q0_1);                          \
    Q1_1 = __builtin_elementwise_fma(c23, dy_, Q1_1);                          \
    Q2_1 = __builtin_elementwise_fma(c23, dz_, Q2_1);                          \
    Q3_1 = __builtin_elementwise_fma(c23, dw_, Q3_1);
#define PKG2                                                                   \
    Q0_2 = __builtin_elementwise_fma(c45, dx_, Q0_2);                          \
    Q1_2 = __builtin_elementwise_fma(c45, dy_, Q1_2);                          \
    Q2_2 = __builtin_elementwise_fma(c45, dz_, Q2_2);                          \
    Q3_2 = __builtin_elementwise_fma(c45, dw_, Q3_2);
#define PKG3                                                                   \
    Q0_3 = __builtin_elementwise_fma(c67, dx_, Q0_3);                          \
    Q1_3 = __builtin_elementwise_fma(c67, dy_, Q1_3);                          \
    Q2_3 = __builtin_elementwise_fma(c67, dz_, Q2_3);                          \
    Q3_3 = __builtin_elementwise_fma(c67, dw_, Q3_3);

#define PKROWR(A0v, A1v, Dv, Ra, Rb, Rc, Rd)                                   \
  { PKSETUP(A0v, A1v, Dv) PKG##Ra PKG##Rb PKG##Rc PKG##Rd }
#define PKROW(A0v, A1v, Dv) PKROWR(A0v, A1v, Dv, 0, 1, 2, 3)

// ---- threefry2x32 block, exactly matching JAX (20 rounds, inject every 4) ----
__device__ __forceinline__ void tf2x32(uint32_t key0, uint32_t key1,
                                       uint32_t& x0, uint32_t& x1) {
  uint32_t ks2 = key0 ^ key1 ^ 0x1BD11BDAu;
  x0 += key0; x1 += key1;
#define TFR(r) { x0 += x1; x1 = (x1 << r) | (x1 >> (32 - r)); x1 ^= x0; }
  TFR(13) TFR(15) TFR(26) TFR(6)
  x0 += key1; x1 += ks2 + 1u;
  TFR(17) TFR(29) TFR(16) TFR(24)
  x0 += ks2;  x1 += key0 + 2u;
  TFR(13) TFR(15) TFR(26) TFR(6)
  x0 += key0; x1 += key1 + 3u;
  TFR(17) TFR(29) TFR(16) TFR(24)
  x0 += key1; x1 += ks2 + 4u;
  TFR(13) TFR(15) TFR(26) TFR(6)
  x0 += ks2;  x1 += key0 + 5u;
#undef TFR
}

__device__ __forceinline__ uint32_t pbits(uint32_t k0, uint32_t k1, uint32_t flat) {
  uint32_t x0 = 0u, x1 = flat;
  tf2x32(k0, k1, x0, x1);
  return x0 ^ x1;
}

// ---- XLA f32 erf_inv (Giles polynomial) ----
__device__ __forceinline__ float erfinv_xla(float x) {
  float w = -log1pf(-x * x);
  float p;
  if (w < 5.0f) {
    w -= 2.5f;
    p = 2.81022636e-08f;
    p = fmaf(p, w, 3.43273939e-07f);
    p = fmaf(p, w, -3.5233877e-06f);
    p = fmaf(p, w, -4.39150654e-06f);
    p = fmaf(p, w, 0.00021858087f);
    p = fmaf(p, w, -0.00125372503f);
    p = fmaf(p, w, -0.00417768164f);
    p = fmaf(p, w, 0.246640727f);
    p = fmaf(p, w, 1.50140941f);
  } else {
    w = sqrtf(w) - 3.0f;
    p = -0.000200214257f;
    p = fmaf(p, w, 0.000100950558f);
    p = fmaf(p, w, 0.00134934322f);
    p = fmaf(p, w, -0.00367342844f);
    p = fmaf(p, w, 0.00573950773f);
    p = fmaf(p, w, -0.0076224613f);
    p = fmaf(p, w, 0.00943887047f);
    p = fmaf(p, w, 1.00167406f);
    p = fmaf(p, w, 2.83297682f);
  }
  return p * x;
}

__device__ __forceinline__ float bits_to_normal(uint32_t bits) {
  uint32_t fb = (bits >> 9) | 0x3F800000u;
  float f = __uint_as_float(fb) - 1.0f;
  const float lo = -0.99999994f;
  float u = fmaf(f, 2.0f, lo);
  u = fmaxf(lo, u);
  return 1.41421356237f * erfinv_xla(u);
}

__device__ __forceinline__ double red32d(double v) {
  v += __shfl_xor(v, 16);
  v += __shfl_xor(v, 8);
  v += __shfl_xor(v, 4);
  v += __shfl_xor(v, 2);
  v += __shfl_xor(v, 1);
  return v;
}

__device__ __forceinline__ int pop64(uint64_t& b) {
  if (b == 0ull) return -1;
  int i = (int)__builtin_ctzll(b);
  b &= b - 1ull;
  return i;
}

template <int CTRL>
__device__ __forceinline__ float dppadd(float s) {
  int v = __builtin_amdgcn_update_dpp(0, __float_as_int(s), CTRL, 0xF, 0xF, true);
  return s + __int_as_float(v);
}

// shared V-row builder (f64 in-thread, bitwise identical to monolithic path)
__device__ __forceinline__ void build_vrow(int b, int row, const float* zin,
                                           const int* is_in, const double* v0D,
                                           double* vrow) {
  const double PI_D = 3.14159265358979323846;
  uint32_t b0 = 0u, b1 = 1u; tf2x32(0u, 42u, b0, b1);
  if (row == 0) {
#pragma unroll
    for (int t = 0; t < 16; ++t) {
      double2 w = *(const double2*)(v0D + 2 * t);
      vrow[2 * t] = w.x; vrow[2 * t + 1] = w.y;
    }
  } else {
    uint32_t base = ((uint32_t)(b * NVARS + row)) * KDIM;
#pragma unroll
    for (int q = 0; q < 32; ++q)
      vrow[q] = (double)bits_to_normal(pbits(b0, b1, base + (uint32_t)q));
    double dot = 0.0;
#pragma unroll
    for (int t = 0; t < 16; ++t) {
      double2 w = *(const double2*)(v0D + 2 * t);
      dot += vrow[2 * t] * w.x + vrow[2 * t + 1] * w.y;
    }
#pragma unroll
    for (int t = 0; t < 16; ++t) {
      double2 w = *(const double2*)(v0D + 2 * t);
      vrow[2 * t]     -= dot * w.x;
      vrow[2 * t + 1] -= dot * w.y;
    }
    double n2 = 0.0;
#pragma unroll
    for (int q = 0; q < 32; ++q) n2 += vrow[q] * vrow[q];
    double rinv = 1.0 / sqrt(n2);
#pragma unroll
    for (int q = 0; q < 32; ++q) vrow[q] *= rinv;
    if (row <= NIN && is_in[b * NIN + row - 1] > 0) {
      double zf = (double)zin[b * NIN + row - 1];
      double cc = cos(PI_D * zf), sn = sin(PI_D * zf);
#pragma unroll
      for (int t = 0; t < 16; ++t) {
        double2 w = *(const double2*)(v0D + 2 * t);
        vrow[2 * t]     = -cc * w.x + sn * vrow[2 * t];
        vrow[2 * t + 1] = -cc * w.y + sn * vrow[2 * t + 1];
      }
    }
  }
}

// ====== fused kernel: V (per-batch, in-LDS) + G quarter -> ws (256 x 1024) =
__global__ __launch_bounds__(1024) void mixnet_vg(
    const float* __restrict__ C32, const float* __restrict__ zin,
    const int* __restrict__ is_in, float* __restrict__ Vw,
    float* __restrict__ Gw) {
  extern __shared__ char smemraw[];
  float*  Vls = (float*)smemraw;               // [1024][32]
  double* v0D = (double*)(smemraw + 131072);   // [32]

  const int tid = threadIdx.x;
  const int b = blockIdx.x >> 2, q = blockIdx.x & 3;

  uint32_t a0 = 0u, a1 = 0u; tf2x32(0u, 42u, a0, a1);
  if (tid < 32) {
    float raw = bits_to_normal(pbits(a0, a1, (uint32_t)(b * KDIM + tid)));
    double n2 = red32d((double)raw * (double)raw);
    v0D[tid] = (double)raw / sqrt(n2);
  }
  __syncthreads();

  {
    double vrow[32];
    build_vrow(b, tid, zin, is_in, v0D, vrow);
    const bool ownq = ((tid >> 8) == q);   // this block owns V quarter q
#pragma unroll
    for (int qq = 0; qq < 8; ++qq) {
      float4 w;
      w.x = (float)vrow[4 * qq];     w.y = (float)vrow[4 * qq + 1];
      w.z = (float)vrow[4 * qq + 2]; w.w = (float)vrow[4 * qq + 3];
      *(float4*)(Vls + tid * 32 + 4 * qq) = w;
      if (ownq)
        *(float4*)(Vw + (size_t)(b * NVARS + tid) * 32 + 4 * qq) = w;
    }
  }
  __syncthreads();

  const int jg2 = tid >> 3, kg = tid & 7;
  const int r0 = q * 256 + 2 * jg2;
  const float* Cb0 = C32 + (size_t)r0 * NVARS;
  const float* Cb1 = Cb0 + NVARS;

  float G0 = 0.f, G1 = 0.f, G2 = 0.f, G3 = 0.f;
  float G4 = 0.f, G5 = 0.f, G6 = 0.f, G7 = 0.f;
  for (int i = 0; i < NVARS; i += 4) {
    float4 c0 = *(const float4*)(Cb0 + i);
    float4 c1 = *(const float4*)(Cb1 + i);
#pragma unroll
    for (int u = 0; u < 4; ++u) {
      float4 vv = *(const float4*)(Vls + (size_t)(i + u) * 32 + 4 * kg);
      float cu0 = (u == 0) ? c0.x : (u == 1) ? c0.y : (u == 2) ? c0.z : c0.w;
      float cu1 = (u == 0) ? c1.x : (u == 1) ? c1.y : (u == 2) ? c1.z : c1.w;
      G0 = fmaf(cu0, vv.x, G0); G1 = fmaf(cu0, vv.y, G1);
      G2 = fmaf(cu0, vv.z, G2); G3 = fmaf(cu0, vv.w, G3);
      G4 = fmaf(cu1, vv.x, G4); G5 = fmaf(cu1, vv.y, G5);
      G6 = fmaf(cu1, vv.z, G6); G7 = fmaf(cu1, vv.w, G7);
    }
  }
  float4 w0; w0.x = G0; w0.y = G1; w0.z = G2; w0.w = G3;
  float4 w1; w1.x = G4; w1.y = G5; w1.z = G6; w1.w = G7;
  *(float4*)(Gw + (size_t)(b * NVARS + r0) * 32 + 4 * kg)     = w0;
  *(float4*)(Gw + (size_t)(b * NVARS + r0 + 1) * 32 + 4 * kg) = w1;
}

// ---- producer row (R11 form: raw rsq, rotated PKROW) ----
#define PROW(iiL, mL, pL, cL, Ra, Rb, Rc, Rd)                                  \
  {                                                                            \
    const bool on = ((iiL) < 32) ? ((myLo >> (iiL)) & 1u)                      \
                                 : ((myHi >> ((iiL) - 32)) & 1u);              \
    if (on) {                                                                  \
      const int row = base + (iiL);                                            \
      float4 c0 = *(const float4*)(Cd + (iiL) * 64 + 8 * jgR);                 \
      float4 c1 = *(const float4*)(Cd + (iiL) * 64 + 8 * jgR + 4);             \
      float4 vold = *(const float4*)(Vs + row * 32 + 4 * kg);                  \
      const float g0 = (Q0_##pL).cL, g1 = (Q1_##pL).cL;                        \
      const float g2 = (Q2_##pL).cL, g3 = (Q3_##pL).cL;                        \
      float s = g0 * g0;                                                       \
      s = fmaf(g1, g1, s); s = fmaf(g2, g2, s); s = fmaf(g3, g3, s);           \
      s = dppadd<0xB1>(s);                                                     \
      s = dppadd<0x4E>(s);                                                     \
      s = dppadd<0x141>(s);                                                    \
      const float sc = fmaxf(s, 1e-24f);                                       \
      const float inv = -__builtin_amdgcn_rsqf(sc);                            \
      float4 vnew, d;                                                          \
      vnew.x = g0 * inv; d.x = vnew.x - vold.x;                                \
      vnew.y = g1 * inv; d.y = vnew.y - vold.y;                                \
      vnew.z = g2 * inv; d.z = vnew.z - vold.z;                                \
      vnew.w = g3 * inv; d.w = vnew.w - vold.w;                                \
      if (jgR == (mL)) *(float4*)(dVs + n * 32 + 4 * kg) = d;                  \
      asm volatile("" ::: "memory");                                           \
      if (lane == 0) progV[spar] = n + 1;                                      \
      float4 dd = *(const float4*)(dVs + n * 32 + 4 * kg);                     \
      if (jgR == (mL)) *(float4*)(Vs + row * 32 + 4 * kg) = vnew;              \
      PKROWR(c0, c1, dd, Ra, Rb, Rc, Rd);                                      \
      ++n;                                                                     \
    }                                                                          \
  }

#define PGRP(mL)                                                               \
  PROW(8 * (mL) + 0, mL, 0, x, 0, 1, 2, 3)                                     \
  PROW(8 * (mL) + 1, mL, 0, y, 1, 2, 3, 0)                                     \
  PROW(8 * (mL) + 2, mL, 1, x, 1, 2, 3, 0)                                     \
  PROW(8 * (mL) + 3, mL, 1, y, 2, 3, 0, 1)                                     \
  PROW(8 * (mL) + 4, mL, 2, x, 2, 3, 0, 1)                                     \
  PROW(8 * (mL) + 5, mL, 2, y, 3, 0, 1, 2)                                     \
  PROW(8 * (mL) + 6, mL, 3, x, 3, 0, 1, 2)                                     \
  PROW(8 * (mL) + 7, mL, 3, y, 0, 1, 2, 3)

// ================= solve kernel (R13 verbatim; 64 blocks x 1024 thr) =======
__global__ __launch_bounds__(1024, 4) void mixnet_solve(
    const float* __restrict__ C32, const float* __restrict__ zin,
    const int* __restrict__ is_in, const float* __restrict__ Vw,
    const float* __restrict__ Gw, float* __restrict__ out) {
  extern __shared__ char smemraw[];
  float*    Vs    = (float*)smemraw;
  float*    Cd    = (float*)(smemraw + 131072);
  float*    dVs   = (float*)(smemraw + 147456);
  uint32_t* fmask = (uint32_t*)(smemraw + 155648);
  double*   v0D   = (double*)(smemraw + 155776);
  volatile int* progV = (volatile int*)(smemraw + 156032);

  const int tid  = threadIdx.x;
  const int b    = blockIdx.x;
  const int jg   = tid >> 3;
  const int kg   = tid & 7;
  const int lane = tid & 63;
  const int wave = tid >> 6;
  const int jgR  = jg & 7;

  uint32_t myLo, myHi;
  {
    int row = tid;
    bool fr;
    if (row == 0) fr = false;
    else if (row <= NIN) fr = (is_in[b * NIN + row - 1] == 0);
    else fr = true;
    unsigned long long m = __ballot(fr);
    myLo = (uint32_t)m; myHi = (uint32_t)(m >> 32);
    if (lane == 0) { fmask[2 * wave] = myLo; fmask[2 * wave + 1] = myHi; }
  }
  if (tid == 0) { progV[0] = 0; progV[1] = 0; }

  uint32_t a0 = 0u, a1 = 0u; tf2x32(0u, 42u, a0, a1);
  if (tid < 32) {
    float raw = bits_to_normal(pbits(a0, a1, (uint32_t)(b * KDIM + tid)));
    double n2 = red32d((double)raw * (double)raw);
    v0D[tid] = (double)raw / sqrt(n2);
  }

  {
    const float* vp = Vw + (size_t)(b * NVARS + tid) * 32;
#pragma unroll
    for (int qq = 0; qq < 8; ++qq)
      *(float4*)(Vs + tid * 32 + 4 * qq) = *(const float4*)(vp + 4 * qq);
  }

  f32x2 Q0_0, Q1_0, Q2_0, Q3_0, Q0_1, Q1_1, Q2_1, Q3_1;
  f32x2 Q0_2, Q1_2, Q2_2, Q3_2, Q0_3, Q1_3, Q2_3, Q3_3;
  {
    const float* gp = Gw + (size_t)(b * NVARS + 8 * jg) * 32 + 4 * kg;
    float4 g0 = *(const float4*)(gp + 0 * 32);
    float4 g1 = *(const float4*)(gp + 1 * 32);
    float4 g2 = *(const float4*)(gp + 2 * 32);
    float4 g3 = *(const float4*)(gp + 3 * 32);
    float4 g4 = *(const float4*)(gp + 4 * 32);
    float4 g5 = *(const float4*)(gp + 5 * 32);
    float4 g6 = *(const float4*)(gp + 6 * 32);
    float4 g7 = *(const float4*)(gp + 7 * 32);
    Q0_0.x = g0.x; Q0_0.y = g1.x; Q1_0.x = g0.y; Q1_0.y = g1.y;
    Q2_0.x = g0.z; Q2_0.y = g1.z; Q3_0.x = g0.w; Q3_0.y = g1.w;
    Q0_1.x = g2.x; Q0_1.y = g3.x; Q1_1.x = g2.y; Q1_1.y = g3.y;
    Q2_1.x = g2.z; Q2_1.y = g3.z; Q3_1.x = g2.w; Q3_1.y = g3.w;
    Q0_2.x = g4.x; Q0_2.y = g5.x; Q1_2.x = g4.y; Q1_2.y = g5.y;
    Q2_2.x = g4.z; Q2_2.y = g5.z; Q3_2.x = g4.w; Q3_2.y = g5.w;
    Q0_3.x = g6.x; Q0_3.y = g7.x; Q1_3.x = g6.y; Q1_3.y = g7.y;
    Q2_3.x = g6.z; Q2_3.y = g7.z; Q3_3.x = g6.w; Q3_3.y = g7.w;
  }
  __syncthreads();

  int spar = 0;
  for (int it = 0; it < MAXIT; ++it) {
    for (int g = 0; g < 16; ++g) {
      {
        int r = tid >> 4, c4 = (tid & 15) << 2;
        float4 cc = *(const float4*)(C32 + (size_t)(64 * g + r) * NVARS
                                     + 64 * g + c4);
        *(float4*)(Cd + r * 64 + c4) = cc;
      }
      const uint32_t fl = fmask[2 * g], fh = fmask[2 * g + 1];
      if (wave == g && lane == 0) progV[spar ^ 1] = 0;
      __syncthreads();

      if (wave == g) {
        __builtin_amdgcn_s_setprio(3);
        int n = 0;
        const int base = 64 * g;
        PGRP(0) PGRP(1) PGRP(2) PGRP(3)
        PGRP(4) PGRP(5) PGRP(6) PGRP(7)
        __builtin_amdgcn_s_setprio(0);
      } else {
        uint64_t pb = ((uint64_t)fh << 32) | (uint64_t)fl;
        const int cnt = (int)__builtin_popcountll(pb);
        float4 cp0[4], cp1[4];
#pragma unroll
        for (int s2 = 0; s2 < 4; ++s2) {
          int r = pop64(pb);
          if (r >= 0) {
            const float* p = C32 + (size_t)(64 * g + r) * NVARS + 8 * jg;
            cp0[s2] = *(const float4*)p; cp1[s2] = *(const float4*)(p + 4);
          }
        }
        int n2 = 0;
        while (n2 < cnt) {
          const int hi = (n2 + 4 < cnt) ? n2 + 4 : cnt;
          while (progV[spar] < hi) __builtin_amdgcn_s_sleep(8);
          if (hi == n2 + 4) {
            float4 dq0 = *(const float4*)(dVs + (n2 + 0) * 32 + 4 * kg);
            float4 dq1 = *(const float4*)(dVs + (n2 + 1) * 32 + 4 * kg);
            float4 dq2 = *(const float4*)(dVs + (n2 + 2) * 32 + 4 * kg);
            float4 dq3 = *(const float4*)(dVs + (n2 + 3) * 32 + 4 * kg);
            PKROW(cp0[0], cp1[0], dq0);
            PKROW(cp0[1], cp1[1], dq1);
            PKROW(cp0[2], cp1[2], dq2);
            PKROW(cp0[3], cp1[3], dq3);
          } else {
#pragma unroll
            for (int s2 = 0; s2 < 4; ++s2) {
              if (n2 + s2 < hi) {
                float4 dv = *(const float4*)(dVs + (n2 + s2) * 32 + 4 * kg);
                PKROW(cp0[s2], cp1[s2], dv);
              }
            }
          }
#pragma unroll
          for (int s2 = 0; s2 < 4; ++s2) {
            int r = pop64(pb);
            if (r >= 0) {
              const float* p = C32 + (size_t)(64 * g + r) * NVARS + 8 * jg;
              cp0[s2] = *(const float4*)p; cp1[s2] = *(const float4*)(p + 4);
            }
          }
          n2 = hi;
        }
      }
      spar ^= 1;
      __syncthreads();
    }
  }

  const double PI_D = 3.14159265358979323846;
  if (tid >= 1 && tid <= NIN) {
    bool fr = (fmask[tid >> 5] >> (tid & 31)) & 1u;
    float zo;
    if (fr) {
      double dot = 0.0;
#pragma unroll
      for (int t = 0; t < 16; ++t) {
        double2 w = *(const double2*)(v0D + 2 * t);
        dot += (double)Vs[tid * 32 + 2 * t] * w.x
             + (double)Vs[tid * 32 + 2 * t + 1] * w.y;
      }
      double ca = fmin(fmax(-dot, -1.0 + 1e-7), 1.0 - 1e-7);
      zo = (float)(acos(ca) / PI_D);
    } else {
      zo = zin[b * NIN + tid - 1];
    }
    out[b * NIN + tid - 1] = zo;
  }
}

// ============== monolithic fallback (R11 verbatim) =========================
__global__ __launch_bounds__(1024, 4) void mixnet_kernel(
    const float* __restrict__ C32, const float* __restrict__ zin,
    const int* __restrict__ is_in, float* __restrict__ out) {
  extern __shared__ char smemraw[];
  float*    Vs    = (float*)smemraw;
  float*    Cd    = (float*)(smemraw + 131072);
  float*    dVs   = (float*)(smemraw + 147456);
  uint32_t* fmask = (uint32_t*)(smemraw + 155648);
  double*   v0D   = (double*)(smemraw + 155776);
  volatile int* progV = (volatile int*)(smemraw + 156032);

  const int tid  = threadIdx.x;
  const int b    = blockIdx.x;
  const int jg   = tid >> 3;
  const int kg   = tid & 7;
  const int lane = tid & 63;
  const int wave = tid >> 6;
  const int jgR  = jg & 7;

  uint32_t myLo, myHi;
  {
    int row = tid;
    bool fr;
    if (row == 0) fr = false;
    else if (row <= NIN) fr = (is_in[b * NIN + row - 1] == 0);
    else fr = true;
    unsigned long long m = __ballot(fr);
    myLo = (uint32_t)m; myHi = (uint32_t)(m >> 32);
    if (lane == 0) { fmask[2 * wave] = myLo; fmask[2 * wave + 1] = myHi; }
  }
  if (tid == 0) { progV[0] = 0; progV[1] = 0; }

  uint32_t a0 = 0u, a1 = 0u; tf2x32(0u, 42u, a0, a1);
  if (tid < 32) {
    float raw = bits_to_normal(pbits(a0, a1, (uint32_t)(b * KDIM + tid)));
    double n2 = red32d((double)raw * (double)raw);
    v0D[tid] = (double)raw / sqrt(n2);
  }
  __syncthreads();

  {
    double vrow[32];
    build_vrow(b, tid, zin, is_in, v0D, vrow);
#pragma unroll
    for (int q = 0; q < 8; ++q) {
      float4 w;
      w.x = (float)vrow[4 * q];     w.y = (float)vrow[4 * q + 1];
      w.z = (float)vrow[4 * q + 2]; w.w = (float)vrow[4 * q + 3];
      *(float4*)(Vs + tid * 32 + 4 * q) = w;
    }
  }
  __syncthreads();

  f32x2 Q0_0, Q1_0, Q2_0, Q3_0, Q0_1, Q1_1, Q2_1, Q3_1;
  f32x2 Q0_2, Q1_2, Q2_2, Q3_2, Q0_3, Q1_3, Q2_3, Q3_3;
  {
    float Gj[32];
#pragma unroll
    for (int q = 0; q < 32; ++q) Gj[q] = 0.f;
    const float* Cb = C32 + (size_t)(8 * jg) * NVARS;
    for (int i = 0; i < NVARS; i += 4) {
      float4 cw[8];
#pragma unroll
      for (int l = 0; l < 8; ++l)
        cw[l] = *(const float4*)(Cb + (size_t)l * NVARS + i);
#pragma unroll
      for (int u = 0; u < 4; ++u) {
        float4 vv = *(const float4*)(Vs + (i + u) * 32 + 4 * kg);
#pragma unroll
        for (int l = 0; l < 8; ++l) {
          float cu = (u == 0) ? cw[l].x : (u == 1) ? cw[l].y
                   : (u == 2) ? cw[l].z : cw[l].w;
          Gj[l * 4 + 0] = fmaf(cu, vv.x, Gj[l * 4 + 0]);
          Gj[l * 4 + 1] = fmaf(cu, vv.y, Gj[l * 4 + 1]);
          Gj[l * 4 + 2] = fmaf(cu, vv.z, Gj[l * 4 + 2]);
          Gj[l * 4 + 3] = fmaf(cu, vv.w, Gj[l * 4 + 3]);
        }
      }
    }
    Q0_0.x = Gj[0];  Q0_0.y = Gj[4];  Q1_0.x = Gj[1];  Q1_0.y = Gj[5];
    Q2_0.x = Gj[2];  Q2_0.y = Gj[6];  Q3_0.x = Gj[3];  Q3_0.y = Gj[7];
    Q0_1.x = Gj[8];  Q0_1.y = Gj[12]; Q1_1.x = Gj[9];  Q1_1.y = Gj[13];
    Q2_1.x = Gj[10]; Q2_1.y = Gj[14]; Q3_1.x = Gj[11]; Q3_1.y = Gj[15];
    Q0_2.x = Gj[16]; Q0_2.y = Gj[20]; Q1_2.x = Gj[17]; Q1_2.y = Gj[21];
    Q2_2.x = Gj[18]; Q2_2.y = Gj[22]; Q3_2.x = Gj[19]; Q3_2.y = Gj[23];
    Q0_3.x = Gj[24]; Q0_3.y = Gj[28]; Q1_3.x = Gj[25]; Q1_3.y = Gj[29];
    Q2_3.x = Gj[26]; Q2_3.y = Gj[30]; Q3_3.x = Gj[27]; Q3_3.y = Gj[31];
  }
  __syncthreads();

  int spar = 0;
  for (int it = 0; it < MAXIT; ++it) {
    for (int g = 0; g < 16; ++g) {
      {
        int r = tid >> 4, c4 = (tid & 15) << 2;
        float4 cc = *(const float4*)(C32 + (size_t)(64 * g + r) * NVARS
                                     + 64 * g + c4);
        *(float4*)(Cd + r * 64 + c4) = cc;
      }
      const uint32_t fl = fmask[2 * g], fh = fmask[2 * g + 1];
      if (wave == g && lane == 0) progV[spar ^ 1] = 0;
      __syncthreads();

      if (wave == g) {
        __builtin_amdgcn_s_setprio(3);
        int n = 0;
        const int base = 64 * g;
        PGRP(0) PGRP(1) PGRP(2) PGRP(3)
        PGRP(4) PGRP(5) PGRP(6) PGRP(7)
        __builtin_amdgcn_s_setprio(0);
      } else {
        uint64_t pb = ((uint64_t)fh << 32) | (uint64_t)fl;
        const int cnt = (int)__builtin_popcountll(pb);
        float4 cp0[4], cp1[4];
#pragma unroll
        for (int s2 = 0; s2 < 4; ++s2) {
          int r = pop64(pb);
          if (r >= 0) {
            const float* p = C32 + (size_t)(64 * g + r) * NVARS + 8 * jg;
            cp0[s2] = *(const float4*)p; cp1[s2] = *(const float4*)(p + 4);
          }
        }
        int n2 = 0;
        while (n2 < cnt) {
          const int hi = (n2 + 4 < cnt) ? n2 + 4 : cnt;
          while (progV[spar] < hi) __builtin_amdgcn_s_sleep(8);
          if (hi == n2 + 4) {
            float4 dq0 = *(const float4*)(dVs + (n2 + 0) * 32 + 4 * kg);
            float4 dq1 = *(const float4*)(dVs + (n2 + 1) * 32 + 4 * kg);
            float4 dq2 = *(const float4*)(dVs + (n2 + 2) * 32 + 4 * kg);
            float4 dq3 = *(const float4*)(dVs + (n2 + 3) * 32 + 4 * kg);
            PKROW(cp0[0], cp1[0], dq0);
            PKROW(cp0[1], cp1[1], dq1);
            PKROW(cp0[2], cp1[2], dq2);
            PKROW(cp0[3], cp1[3], dq3);
          } else {
#pragma unroll
            for (int s2 = 0; s2 < 4; ++s2) {
              if (n2 + s2 < hi) {
                float4 dv = *(const float4*)(dVs + (n2 + s2) * 32 + 4 * kg);
                PKROW(cp0[s2], cp1[s2], dv);
              }
            }
          }
#pragma unroll
          for (int s2 = 0; s2 < 4; ++s2) {
            int r = pop64(pb);
            if (r >= 0) {
              const float* p = C32 + (size_t)(64 * g + r) * NVARS + 8 * jg;
              cp0[s2] = *(const float4*)p; cp1[s2] = *(const float4*)(p + 4);
            }
          }
          n2 = hi;
        }
      }
      spar ^= 1;
      __syncthreads();
    }
  }

  const double PI_D = 3.14159265358979323846;
  if (tid >= 1 && tid <= NIN) {
    bool fr = (fmask[tid >> 5] >> (tid & 31)) & 1u;
    float zo;
    if (fr) {
      double dot = 0.0;
#pragma unroll
      for (int t = 0; t < 16; ++t) {
        double2 w = *(const double2*)(v0D + 2 * t);
        dot += (double)Vs[tid * 32 + 2 * t] * w.x
             + (double)Vs[tid * 32 + 2 * t + 1] * w.y;
      }
      double ca = fmin(fmax(-dot, -1.0 + 1e-7), 1.0 - 1e-7);
      zo = (float)(acos(ca) / PI_D);
    } else {
      zo = zin[b * NIN + tid - 1];
    }
    out[b * NIN + tid - 1] = zo;
  }
}

extern "C" void kernel_launch(void* const* d_in, const int* in_sizes, int n_in,
                              void* d_out, int out_size, void* d_ws, size_t ws_size,
                              hipStream_t stream) {
  const float* C        = (const float*)d_in[0];
  const float* z        = (const float*)d_in[1];
  const int*   is_input = (const int*)d_in[2];
  float*       out      = (float*)d_out;

  (void)hipFuncSetAttribute((const void*)mixnet_vg,
                            hipFuncAttributeMaxDynamicSharedMemorySize,
                            VG_SMEM);
  (void)hipFuncSetAttribute((const void*)mixnet_solve,
                            hipFuncAttributeMaxDynamicSharedMemorySize,
                            SMEM_BYTES);
  (void)hipFuncSetAttribute((const void*)mixnet_kernel,
                            hipFuncAttributeMaxDynamicSharedMemorySize,
                            SMEM_BYTES);

  if (d_ws != nullptr && ws_size >= WS_NEEDED) {
    float* Vw = (float*)((char*)d_ws + WS_V_OFF);
    float* Gw = (float*)((char*)d_ws + WS_G_OFF);
    mixnet_vg<<<256, 1024, VG_SMEM, stream>>>(C, z, is_input, Vw, Gw);
    mixnet_solve<<<BATCH, 1024, SMEM_BYTES, stream>>>(C, z, is_input, Vw, Gw, out);
  } else {
    mixnet_kernel<<<BATCH, 1024, SMEM_BYTES, stream>>>(C, z, is_input, out);
  }
}